// Round 4
// baseline (1149.114 us; speedup 1.0000x reference)
//
#include <hip/hip_runtime.h>
#include <math.h>

// StatisticalFeatureLoss — R3: scatter-accumulate pipeline, zero LDS, zero
// shift moves. 1 col/lane; vertical convs land in K rotating per-row
// accumulators via FMA-scatter; row loop unrolled by D=3R+1 so all ring
// indices are literals (slot lifecycle: overwrite r-R .. emit r+2R, reuse
// r+2R+1 — exactly back-to-back). Horizontal convs via ds_bpermute.

static constexpr int H = 512, W = 512, PLANES = 48;
static constexpr float EPSF = 1e-8f;

__global__ void init_acc_kernel(double* acc) {
    if (threadIdx.x < 4) acc[threadIdx.x] = 0.0;
}

__global__ void final_kernel(const double* __restrict__ acc, float* __restrict__ out) {
    if (threadIdx.x == 0) {
        const double npix = (double)PLANES * H * W;
        double tot = acc[0] + acc[1] + 0.5 * acc[2] + 0.001 * acc[3];
        out[0] = (float)(tot / (npix * 12.0));
    }
}

__device__ __forceinline__ float bperm(int addr, float v) {
    return __int_as_float(__builtin_amdgcn_ds_bpermute(addr, __float_as_int(v)));
}

template <int K, int BAND, int D, int DX, int NSTRIP>
__global__ __launch_bounds__(64)
void stat_kernel(const float* __restrict__ pred, const float* __restrict__ targ,
                 double* __restrict__ acc) {
    constexpr int R  = K / 2;
    constexpr int OW = 64 - 4 * R;            // valid output cols per strip
    constexpr int NBAND = H / BAND;
    constexpr int T  = BAND + 4 * R;          // real iterations
    constexpr int Tp = ((T + D - 1) / D) * D; // padded to unroll multiple

    const int b     = blockIdx.x;
    const int band  = b % NBAND;
    const int tmp   = b / NBAND;
    const int strip = tmp % NSTRIP;
    const int plane = tmp / NSTRIP;
    const int t     = threadIdx.x;
    const int gc0   = strip * OW - 2 * R + t; // this lane's global col
    const int rb0   = band * BAND;
    const int y0    = rb0 - 2 * R;

    const bool  iva     = (unsigned)gc0 < (unsigned)W;
    const float colmask = iva ? 1.f : 0.f;
    const float emask   = (t >= 2 * R && t < 2 * R + OW && gc0 < W) ? 1.f : 0.f;

    int adr[K];
#pragma unroll
    for (int j = 0; j < K; ++j) adr[j] = (t - R + j) << 2;

    // Gaussian weights (reference numerics; symmetric bitwise), in SGPRs
    float g[K];
    {
        const float sigma = (float)K / 6.0f;
        const float inv2s2 = 1.0f / (2.0f * sigma * sigma);
        float s = 0.0f;
#pragma unroll
        for (int i = 0; i < K; ++i) {
            float c = (float)(i - K / 2);
            g[i] = expf(-c * c * inv2s2);
            s += g[i];
        }
#pragma unroll
        for (int i = 0; i < K; ++i)
            g[i] = __int_as_float(__builtin_amdgcn_readfirstlane(__float_as_int(g[i] / s)));
    }

    const float* src0 = pred + (size_t)plane * H * W + gc0;
    const float* src1 = targ + (size_t)plane * H * W + gc0;

    auto loadrow = [&](int s, int y) -> float {
        float v = 0.f;
        if (iva && (unsigned)y < (unsigned)H)
            v = (s == 0 ? src0 : src1)[(long)y << 9];
        return v;
    };

    // Rotating accumulators (all constant-indexed after unroll)
    float mn[2][D], msq[2][D], m3a[2][D], m4a[2][D], xr[2][DX];
    float featp[4];
    float sums[4] = {0.f, 0.f, 0.f, 0.f};
    float pf[2] = { loadrow(0, y0), loadrow(1, y0) };

    for (int yy = 0; yy < Tp; yy += D) {
#pragma unroll
        for (int u = 0; u < D; ++u) {
            const int i = yy + u;        // iteration index; i % D == u
            const int y = y0 + i;        // input row consumed this iter
            const float rmask = (((unsigned)(y - R) < (unsigned)H) ? 1.f : 0.f) * colmask;
#pragma unroll
            for (int s = 0; s < 2; ++s) {
                const float x = pf[s];
                pf[s] = loadrow(s, y + 1);            // distance-1 prefetch
                xr[s][u % DX] = x;

                // horizontal convs of x and x^2 (zero-padded x)
                float w[K];
#pragma unroll
                for (int j = 0; j < K; ++j) w[j] = (j == R) ? x : bperm(adr[j], x);
                float hx = 0.f, hq = 0.f;
#pragma unroll
                for (int j = 0; j < K; ++j) { hx += g[j] * w[j]; hq += g[j] * (w[j] * w[j]); }

                // scatter into mean/msq accumulators; row y-R+d gets g[d]*hx.
                // d==K-1 is row y+R's FIRST contribution -> overwrite (no resets)
#pragma unroll
                for (int d = 0; d < K; ++d) {
                    const int sl = (u + d - R + 2 * D) % D;
                    if (d == K - 1) { mn[s][sl] = g[d] * hx; msq[s][sl] = g[d] * hq; }
                    else           { mn[s][sl] += g[d] * hx; msq[s][sl] += g[d] * hq; }
                }

                // mean[y-R] completed by the d==0 term above; build u3/u4 there.
                // (xc FIELD is zero-padded for the m3/m4 convs -> rmask)
                const float xold  = xr[s][(u - R + 2 * DX) % DX];
                const float mean1 = mn[s][(u - R + 2 * D) % D];
                const float xc  = xold - mean1;
                const float xc2 = xc * xc;
                const float u3  = xc2 * xc * rmask;
                const float u4  = xc2 * xc2 * rmask;

                float w3[K], w4[K];
#pragma unroll
                for (int j = 0; j < K; ++j) {
                    w3[j] = (j == R) ? u3 : bperm(adr[j], u3);
                    w4[j] = (j == R) ? u4 : bperm(adr[j], u4);
                }
                float v3 = 0.f, v4 = 0.f;
#pragma unroll
                for (int j = 0; j < K; ++j) { v3 += g[j] * w3[j]; v4 += g[j] * w4[j]; }

                // scatter v3/v4 (row y-R of the u-fields) into m3/m4 accs:
                // row y-2R+d gets g[d]*v3; d==K-1 (row y) is first -> overwrite
#pragma unroll
                for (int d = 0; d < K; ++d) {
                    const int sl = (u + d - 2 * R + 2 * D) % D;
                    if (d == K - 1) { m3a[s][sl] = g[d] * v3; m4a[s][sl] = g[d] * v4; }
                    else           { m3a[s][sl] += g[d] * v3; m4a[s][sl] += g[d] * v4; }
                }

                // emit output row c2 = y-2R (all four accs complete this iter)
                if (i >= 4 * R && i < T) {
                    const int se = (u - 2 * R + 2 * D) % D;
                    const float mean = mn[s][se];
                    const float var  = fmaxf(msq[s][se] - mean * mean, EPSF);
                    const float sd   = sqrtf(var);
                    const float skew = __fdividef(m3a[s][se], sd * var + EPSF);
                    const float kurt = __fdividef(m4a[s][se], var * var + EPSF);
                    if (s == 0) {
                        featp[0] = mean; featp[1] = var; featp[2] = skew; featp[3] = kurt;
                    } else {
                        sums[0] += fabsf(featp[0] - mean);
                        sums[1] += fabsf(featp[1] - var);
                        sums[2] += fabsf(featp[2] - skew);
                        sums[3] += fabsf(featp[3] - kurt);
                    }
                }
            }
        }
    }

    // edge/duplicate lanes masked once at the end (all values finite)
#pragma unroll
    for (int f = 0; f < 4; ++f) {
        float v = sums[f] * emask;
#pragma unroll
        for (int off = 32; off > 0; off >>= 1) v += __shfl_down(v, off, 64);
        if (t == 0) atomicAdd(&acc[f], (double)v);
    }
}

extern "C" void kernel_launch(void* const* d_in, const int* in_sizes, int n_in,
                              void* d_out, int out_size, void* d_ws, size_t ws_size,
                              hipStream_t stream) {
    const float* pred = (const float*)d_in[0];
    const float* targ = (const float*)d_in[1];
    double* acc = (double*)d_ws;
    float* out = (float*)d_out;

    init_acc_kernel<<<1, 64, 0, stream>>>(acc);

    // K, BAND, D(=3R+1), DX(x-ring, divides D, > R), NSTRIP(= ceil(512/OW))
    stat_kernel<3, 32,  4, 2,  9><<<dim3(PLANES *  9 * 16), 64, 0, stream>>>(pred, targ, acc);
    stat_kernel<5, 32,  7, 7, 10><<<dim3(PLANES * 10 * 16), 64, 0, stream>>>(pred, targ, acc);
    stat_kernel<7, 64, 10, 5, 10><<<dim3(PLANES * 10 *  8), 64, 0, stream>>>(pred, targ, acc);

    final_kernel<<<1, 64, 0, stream>>>(acc, out);
}

// Round 5
// 451.881 us; speedup vs baseline: 2.5430x; 2.5430x over previous
//
#include <hip/hip_runtime.h>
#include <math.h>

// StatisticalFeatureLoss — R4: R3's scatter-accumulate pipeline (zero LDS
// arrays, zero shift moves, ring indices folded to literals by D-unroll) +
// two fixes: (a) exchange masked xc ONCE (neighbor powers computed locally)
// -> 2(K-1) bperms/px instead of 3(K-1); (b) 4 independent waves per
// 256-thread block to lift the workgroup-slot occupancy cap.

static constexpr int H = 512, W = 512, PLANES = 48;
static constexpr float EPSF = 1e-8f;

__global__ void init_acc_kernel(double* acc) {
    if (threadIdx.x < 4) acc[threadIdx.x] = 0.0;
}

__global__ void final_kernel(const double* __restrict__ acc, float* __restrict__ out) {
    if (threadIdx.x == 0) {
        const double npix = (double)PLANES * H * W;
        double tot = acc[0] + acc[1] + 0.5 * acc[2] + 0.001 * acc[3];
        out[0] = (float)(tot / (npix * 12.0));
    }
}

__device__ __forceinline__ float bperm(int addr, float v) {
    return __int_as_float(__builtin_amdgcn_ds_bpermute(addr, __float_as_int(v)));
}

template <int K, int BAND, int D, int DX, int NSTRIP>
__global__ __launch_bounds__(256)
void stat_kernel(const float* __restrict__ pred, const float* __restrict__ targ,
                 double* __restrict__ acc) {
    constexpr int R  = K / 2;
    constexpr int OW = 64 - 4 * R;            // valid output cols per strip
    constexpr int NBAND = H / BAND;
    constexpr int T  = BAND + 4 * R;          // real iterations
    constexpr int Tp = ((T + D - 1) / D) * D; // padded to unroll multiple

    const int wv    = threadIdx.x >> 6;       // wave within block
    const int wid   = blockIdx.x * 4 + wv;    // global wave id
    const int band  = wid % NBAND;
    const int tmp   = wid / NBAND;
    const int strip = tmp % NSTRIP;
    const int plane = tmp / NSTRIP;
    const int t     = threadIdx.x & 63;       // lane
    const int gc0   = strip * OW - 2 * R + t; // this lane's global col
    const int y0    = band * BAND - 2 * R;

    const bool  iva     = (unsigned)gc0 < (unsigned)W;
    const float colmask = iva ? 1.f : 0.f;
    const float emask   = (t >= 2 * R && t < 2 * R + OW && gc0 < W) ? 1.f : 0.f;

    // bpermute addresses are block-local (byte addr of lane within the BLOCK's
    // 256-lane window? No: ds_bpermute indexes within the WAVE). t is the
    // wave-lane -> addresses stay wave-relative.
    int adr[K];
#pragma unroll
    for (int j = 0; j < K; ++j) adr[j] = (t - R + j) << 2;

    // Gaussian weights (reference numerics), lane-uniform in SGPRs
    float g[K];
    {
        const float sigma = (float)K / 6.0f;
        const float inv2s2 = 1.0f / (2.0f * sigma * sigma);
        float s = 0.0f;
#pragma unroll
        for (int i = 0; i < K; ++i) {
            float c = (float)(i - K / 2);
            g[i] = expf(-c * c * inv2s2);
            s += g[i];
        }
#pragma unroll
        for (int i = 0; i < K; ++i)
            g[i] = __int_as_float(__builtin_amdgcn_readfirstlane(__float_as_int(g[i] / s)));
    }

    const float* src0 = pred + (size_t)plane * H * W + gc0;
    const float* src1 = targ + (size_t)plane * H * W + gc0;

    auto loadrow = [&](int s, int y) -> float {
        float v = 0.f;
        if (iva && (unsigned)y < (unsigned)H)
            v = (s == 0 ? src0 : src1)[(long)y << 9];
        return v;
    };

    // Rotating accumulators (constant-indexed after the D-unroll)
    float mn[2][D], msq[2][D], m3a[2][D], m4a[2][D], xr[2][DX];
    float featp[4];
    float sums[4] = {0.f, 0.f, 0.f, 0.f};
    float pf[2] = { loadrow(0, y0), loadrow(1, y0) };

    for (int yy = 0; yy < Tp; yy += D) {
#pragma unroll
        for (int u = 0; u < D; ++u) {
            const int i = yy + u;        // iteration index; i % D == u
            const int y = y0 + i;        // input row consumed this iter
            const float rmask = (((unsigned)(y - R) < (unsigned)H) ? 1.f : 0.f) * colmask;
#pragma unroll
            for (int s = 0; s < 2; ++s) {
                const float x = pf[s];
                pf[s] = loadrow(s, y + 1);            // distance-1 prefetch
                xr[s][u % DX] = x;

                // horizontal convs of x and x^2 (zero-padded x)
                float w[K];
#pragma unroll
                for (int j = 0; j < K; ++j) w[j] = (j == R) ? x : bperm(adr[j], x);
                float hx = 0.f, hq = 0.f;
#pragma unroll
                for (int j = 0; j < K; ++j) { hx += g[j] * w[j]; hq += g[j] * (w[j] * w[j]); }

                // scatter into mean/msq accumulators; row y-R+d gets g[d]*hx.
                // d==K-1 is row y+R's FIRST contribution -> overwrite (no resets)
#pragma unroll
                for (int d = 0; d < K; ++d) {
                    const int sl = (u + d - R + 2 * D) % D;
                    if (d == K - 1) { mn[s][sl] = g[d] * hx; msq[s][sl] = g[d] * hq; }
                    else           { mn[s][sl] += g[d] * hx; msq[s][sl] += g[d] * hq; }
                }

                // mean[y-R] completed by the d==0 term; build masked xc there.
                // ONE exchange of xcm; neighbors' cubes/quads computed locally
                // ((xc*m)^3 == xc^2*xc * m bitwise for m in {0,1}).
                const float xold  = xr[s][(u - R + 2 * DX) % DX];
                const float mean1 = mn[s][(u - R + 2 * D) % D];
                const float xcm   = (xold - mean1) * rmask;

                float wc[K];
#pragma unroll
                for (int j = 0; j < K; ++j) wc[j] = (j == R) ? xcm : bperm(adr[j], xcm);
                float v3 = 0.f, v4 = 0.f;
#pragma unroll
                for (int j = 0; j < K; ++j) {
                    const float c2 = wc[j] * wc[j];
                    v3 += g[j] * (c2 * wc[j]);
                    v4 += g[j] * (c2 * c2);
                }

                // scatter v3/v4 (row y-R of the u-fields) into m3/m4 accs:
                // row y-2R+d gets g[d]*v3; d==K-1 (row y) is first -> overwrite
#pragma unroll
                for (int d = 0; d < K; ++d) {
                    const int sl = (u + d - 2 * R + 2 * D) % D;
                    if (d == K - 1) { m3a[s][sl] = g[d] * v3; m4a[s][sl] = g[d] * v4; }
                    else           { m3a[s][sl] += g[d] * v3; m4a[s][sl] += g[d] * v4; }
                }

                // emit output row c2 = y-2R (all four accs complete this iter)
                if (i >= 4 * R && i < T) {
                    const int se = (u - 2 * R + 2 * D) % D;
                    const float mean = mn[s][se];
                    const float var  = fmaxf(msq[s][se] - mean * mean, EPSF);
                    const float sd   = sqrtf(var);
                    const float skew = __fdividef(m3a[s][se], sd * var + EPSF);
                    const float kurt = __fdividef(m4a[s][se], var * var + EPSF);
                    if (s == 0) {
                        featp[0] = mean; featp[1] = var; featp[2] = skew; featp[3] = kurt;
                    } else {
                        sums[0] += fabsf(featp[0] - mean);
                        sums[1] += fabsf(featp[1] - var);
                        sums[2] += fabsf(featp[2] - skew);
                        sums[3] += fabsf(featp[3] - kurt);
                    }
                }
            }
        }
    }

    // per-wave reduction, then one cross-wave LDS pass, 4 atomics per block
    __shared__ float red[4][4];   // [wave][feature]
#pragma unroll
    for (int f = 0; f < 4; ++f) {
        float v = sums[f] * emask;
#pragma unroll
        for (int off = 32; off > 0; off >>= 1) v += __shfl_down(v, off, 64);
        if (t == 0) red[wv][f] = v;
    }
    __syncthreads();
    if (threadIdx.x < 4) {
        float v = red[0][threadIdx.x] + red[1][threadIdx.x]
                + red[2][threadIdx.x] + red[3][threadIdx.x];
        atomicAdd(&acc[threadIdx.x], (double)v);
    }
}

extern "C" void kernel_launch(void* const* d_in, const int* in_sizes, int n_in,
                              void* d_out, int out_size, void* d_ws, size_t ws_size,
                              hipStream_t stream) {
    const float* pred = (const float*)d_in[0];
    const float* targ = (const float*)d_in[1];
    double* acc = (double*)d_ws;
    float* out = (float*)d_out;

    init_acc_kernel<<<1, 64, 0, stream>>>(acc);

    // K, BAND, D(=3R+1), DX(| D, > R), NSTRIP(= ceil(512/OW)); 4 waves/block
    stat_kernel<3, 32,  4, 2,  9><<<dim3(PLANES *  9 * 16 / 4), 256, 0, stream>>>(pred, targ, acc);
    stat_kernel<5, 32,  7, 7, 10><<<dim3(PLANES * 10 * 16 / 4), 256, 0, stream>>>(pred, targ, acc);
    stat_kernel<7, 64, 10, 5, 10><<<dim3(PLANES * 10 *  8 / 4), 256, 0, stream>>>(pred, targ, acc);

    final_kernel<<<1, 64, 0, stream>>>(acc, out);
}

// Round 6
// 440.727 us; speedup vs baseline: 2.6073x; 1.0253x over previous
//
#include <hip/hip_runtime.h>
#include <math.h>

// StatisticalFeatureLoss — R5: R4's scatter-accumulate pipeline + DEEP
// register prefetch (P iterations ahead, P | D so ring indices fold).
// R4 diagnosis: per-iter cost was K-independent => dominated by the
// distance-1 prefetch's vmcnt stall (~200-900 cyc load latency, ~4
// waves/SIMD). pfbuf gives 4-7 rows (~2-3k cyc) of latency slack.

static constexpr int H = 512, W = 512, PLANES = 48;
static constexpr float EPSF = 1e-8f;

__global__ void init_acc_kernel(double* acc) {
    if (threadIdx.x < 4) acc[threadIdx.x] = 0.0;
}

__global__ void final_kernel(const double* __restrict__ acc, float* __restrict__ out) {
    if (threadIdx.x == 0) {
        const double npix = (double)PLANES * H * W;
        double tot = acc[0] + acc[1] + 0.5 * acc[2] + 0.001 * acc[3];
        out[0] = (float)(tot / (npix * 12.0));
    }
}

__device__ __forceinline__ float bperm(int addr, float v) {
    return __int_as_float(__builtin_amdgcn_ds_bpermute(addr, __float_as_int(v)));
}

template <int K, int BAND, int D, int DX, int P, int NSTRIP>
__global__ __launch_bounds__(256)
void stat_kernel(const float* __restrict__ pred, const float* __restrict__ targ,
                 double* __restrict__ acc) {
    constexpr int R  = K / 2;
    constexpr int OW = 64 - 4 * R;            // valid output cols per strip
    constexpr int NBAND = H / BAND;
    constexpr int T  = BAND + 4 * R;          // real iterations
    constexpr int Tp = ((T + D - 1) / D) * D; // padded to unroll multiple
    static_assert(D % P == 0 && D % DX == 0, "index folding needs P|D, DX|D");

    const int wv    = threadIdx.x >> 6;       // wave within block
    const int wid   = blockIdx.x * 4 + wv;    // global wave id
    const int band  = wid % NBAND;
    const int tmp   = wid / NBAND;
    const int strip = tmp % NSTRIP;
    const int plane = tmp / NSTRIP;
    const int t     = threadIdx.x & 63;       // lane
    const int gc0   = strip * OW - 2 * R + t; // this lane's global col
    const int y0    = band * BAND - 2 * R;

    const bool  iva     = (unsigned)gc0 < (unsigned)W;
    const float colmask = iva ? 1.f : 0.f;
    const float emask   = (t >= 2 * R && t < 2 * R + OW && gc0 < W) ? 1.f : 0.f;

    int adr[K];   // ds_bpermute lane byte-addresses (wave-relative)
#pragma unroll
    for (int j = 0; j < K; ++j) adr[j] = (t - R + j) << 2;

    // Gaussian weights (reference numerics), lane-uniform in SGPRs
    float g[K];
    {
        const float sigma = (float)K / 6.0f;
        const float inv2s2 = 1.0f / (2.0f * sigma * sigma);
        float s = 0.0f;
#pragma unroll
        for (int i = 0; i < K; ++i) {
            float c = (float)(i - K / 2);
            g[i] = expf(-c * c * inv2s2);
            s += g[i];
        }
#pragma unroll
        for (int i = 0; i < K; ++i)
            g[i] = __int_as_float(__builtin_amdgcn_readfirstlane(__float_as_int(g[i] / s)));
    }

    const float* src0 = pred + (size_t)plane * H * W + gc0;
    const float* src1 = targ + (size_t)plane * H * W + gc0;

    auto loadrow = [&](int s, int y) -> float {
        float v = 0.f;
        if (iva && (unsigned)y < (unsigned)H)
            v = (s == 0 ? src0 : src1)[(long)y << 9];
        return v;
    };

    // Rotating accumulators (constant-indexed after the D-unroll)
    float mn[2][D], msq[2][D], m3a[2][D], m4a[2][D], xr[2][DX];
    float pfbuf[2][P];                        // deep prefetch ring
    float featp[4];
    float sums[4] = {0.f, 0.f, 0.f, 0.f};

#pragma unroll
    for (int j = 0; j < P; ++j) {             // warmup: rows y0 .. y0+P-1
        pfbuf[0][j] = loadrow(0, y0 + j);
        pfbuf[1][j] = loadrow(1, y0 + j);
    }

    for (int yy = 0; yy < Tp; yy += D) {
#pragma unroll
        for (int u = 0; u < D; ++u) {
            const int i = yy + u;        // iteration index; i % D == u (D|yy)
            const int y = y0 + i;        // input row consumed this iter
            const float rmask = (((unsigned)(y - R) < (unsigned)H) ? 1.f : 0.f) * colmask;
#pragma unroll
            for (int s = 0; s < 2; ++s) {
                const float x = pfbuf[s][u % P];          // row y (loaded P ago)
                pfbuf[s][u % P] = loadrow(s, y + P);      // distance-P prefetch
                xr[s][u % DX] = x;

                // horizontal convs of x and x^2 (zero-padded x)
                float w[K];
#pragma unroll
                for (int j = 0; j < K; ++j) w[j] = (j == R) ? x : bperm(adr[j], x);
                float hx = 0.f, hq = 0.f;
#pragma unroll
                for (int j = 0; j < K; ++j) { hx += g[j] * w[j]; hq += g[j] * (w[j] * w[j]); }

                // scatter into mean/msq accumulators; row y-R+d gets g[d]*hx.
                // d==K-1 is row y+R's FIRST contribution -> overwrite (no resets)
#pragma unroll
                for (int d = 0; d < K; ++d) {
                    const int sl = (u + d - R + 2 * D) % D;
                    if (d == K - 1) { mn[s][sl] = g[d] * hx; msq[s][sl] = g[d] * hq; }
                    else           { mn[s][sl] += g[d] * hx; msq[s][sl] += g[d] * hq; }
                }

                // mean[y-R] completed by the d==0 term; build masked xc there.
                // ONE exchange of xcm; neighbor powers computed locally.
                const float xold  = xr[s][(u - R + 2 * DX) % DX];
                const float mean1 = mn[s][(u - R + 2 * D) % D];
                const float xcm   = (xold - mean1) * rmask;

                float wc[K];
#pragma unroll
                for (int j = 0; j < K; ++j) wc[j] = (j == R) ? xcm : bperm(adr[j], xcm);
                float v3 = 0.f, v4 = 0.f;
#pragma unroll
                for (int j = 0; j < K; ++j) {
                    const float c2 = wc[j] * wc[j];
                    v3 += g[j] * (c2 * wc[j]);
                    v4 += g[j] * (c2 * c2);
                }

                // scatter v3/v4 (row y-R of the u-fields) into m3/m4 accs:
                // row y-2R+d gets g[d]*v3; d==K-1 (row y) is first -> overwrite
#pragma unroll
                for (int d = 0; d < K; ++d) {
                    const int sl = (u + d - 2 * R + 2 * D) % D;
                    if (d == K - 1) { m3a[s][sl] = g[d] * v3; m4a[s][sl] = g[d] * v4; }
                    else           { m3a[s][sl] += g[d] * v3; m4a[s][sl] += g[d] * v4; }
                }

                // emit output row c2 = y-2R (all four accs complete this iter)
                if (i >= 4 * R && i < T) {
                    const int se = (u - 2 * R + 2 * D) % D;
                    const float mean = mn[s][se];
                    const float var  = fmaxf(msq[s][se] - mean * mean, EPSF);
                    const float sd   = sqrtf(var);
                    const float skew = __fdividef(m3a[s][se], sd * var + EPSF);
                    const float kurt = __fdividef(m4a[s][se], var * var + EPSF);
                    if (s == 0) {
                        featp[0] = mean; featp[1] = var; featp[2] = skew; featp[3] = kurt;
                    } else {
                        sums[0] += fabsf(featp[0] - mean);
                        sums[1] += fabsf(featp[1] - var);
                        sums[2] += fabsf(featp[2] - skew);
                        sums[3] += fabsf(featp[3] - kurt);
                    }
                }
            }
        }
    }

    // per-wave reduction, then one cross-wave LDS pass, 4 atomics per block
    __shared__ float red[4][4];   // [wave][feature]
#pragma unroll
    for (int f = 0; f < 4; ++f) {
        float v = sums[f] * emask;
#pragma unroll
        for (int off = 32; off > 0; off >>= 1) v += __shfl_down(v, off, 64);
        if (t == 0) red[wv][f] = v;
    }
    __syncthreads();
    if (threadIdx.x < 4) {
        float v = red[0][threadIdx.x] + red[1][threadIdx.x]
                + red[2][threadIdx.x] + red[3][threadIdx.x];
        atomicAdd(&acc[threadIdx.x], (double)v);
    }
}

extern "C" void kernel_launch(void* const* d_in, const int* in_sizes, int n_in,
                              void* d_out, int out_size, void* d_ws, size_t ws_size,
                              hipStream_t stream) {
    const float* pred = (const float*)d_in[0];
    const float* targ = (const float*)d_in[1];
    double* acc = (double*)d_ws;
    float* out = (float*)d_out;

    init_acc_kernel<<<1, 64, 0, stream>>>(acc);

    // K, BAND, D(=3R+1), DX(|D, >R), P(|D, prefetch depth), NSTRIP; 4 waves/block
    stat_kernel<3, 32,  4, 2, 4,  9><<<dim3(PLANES *  9 * 16 / 4), 256, 0, stream>>>(pred, targ, acc);
    stat_kernel<5, 32,  7, 7, 7, 10><<<dim3(PLANES * 10 * 16 / 4), 256, 0, stream>>>(pred, targ, acc);
    stat_kernel<7, 64, 10, 5, 5, 10><<<dim3(PLANES * 10 *  8 / 4), 256, 0, stream>>>(pred, targ, acc);

    final_kernel<<<1, 64, 0, stream>>>(acc, out);
}